// Round 3
// baseline (264.815 us; speedup 1.0000x reference)
//
#include <hip/hip_runtime.h>
#include <stdint.h>

typedef __attribute__((ext_vector_type(8))) __bf16 bf16x8;
typedef __attribute__((ext_vector_type(4))) float floatx4;

// ---------- helpers ----------

__device__ __forceinline__ unsigned short f2bf(float f) {
    unsigned int u = __float_as_uint(f);
    u += 0x7FFFu + ((u >> 16) & 1u);   // RNE
    return (unsigned short)(u >> 16);
}
__device__ __forceinline__ unsigned int pack2bf(float lo, float hi) {
    return (unsigned int)f2bf(lo) | ((unsigned int)f2bf(hi) << 16);
}
// truncating f32->bf16 pack of two values in ONE v_perm_b32
__device__ __forceinline__ unsigned int packtrunc(float lo, float hi) {
    return __builtin_amdgcn_perm(__float_as_uint(hi), __float_as_uint(lo), 0x07060302u);
}

__device__ __forceinline__ void gl_lds16(const void* g, void* l) {
    __builtin_amdgcn_global_load_lds(
        (const __attribute__((address_space(1))) void*)g,
        (__attribute__((address_space(3))) void*)l, 16, 0, 0);
}

// ---------- fp32 -> bf16 convert (x + all 4 weights in one launch) ----------

__global__ void cvt_all(const float* __restrict__ x,  const float* __restrict__ wq,
                        const float* __restrict__ wk, const float* __restrict__ wv,
                        const float* __restrict__ wo,
                        unsigned short* __restrict__ xb,  unsigned short* __restrict__ wqb,
                        unsigned short* __restrict__ wkb, unsigned short* __restrict__ wvb,
                        unsigned short* __restrict__ wob) {
    int i = blockIdx.x * blockDim.x + threadIdx.x;   // float4 index, 3145728 total
    const float* in; unsigned short* out; int idx;
    if (i < 2097152) { in = x; out = xb; idx = i; }
    else {
        int j = i - 2097152; int wsel = j >> 18; idx = j & 262143;
        in  = (wsel == 0) ? wq  : (wsel == 1) ? wk  : (wsel == 2) ? wv  : wo;
        out = (wsel == 0) ? wqb : (wsel == 1) ? wkb : (wsel == 2) ? wvb : wob;
    }
    float4 v = ((const float4*)in)[idx];
    ushort4 o;
    o.x = f2bf(v.x); o.y = f2bf(v.y); o.z = f2bf(v.z); o.w = f2bf(v.w);
    ((ushort4*)out)[idx] = o;
}

// ---------- GEMM: C = A @ W^T  (A: (M,1024) bf16 rm, W: (N,1024) bf16 rm)
// MODE 0: Q/K projection + RoPE, TRANSPOSED orientation (d on reg axis).
// MODE 2: V projection, orientation-1 (tokens on reg axis) -> packed V^T stores.
// MODE 1: out-proj, transposed orientation, float4 fp32 stores.
//
// v3 main loop: TRIPLE-buffered LDS, stage 2 tiles ahead, raw s_barrier with
// counted s_waitcnt vmcnt(4) (never 0 until the last iteration). Per-thread
// VMEM queue at iteration top is uniformly [tile t: 4][tile t+1: 4], so
// vmcnt(4) completes exactly tile t while tile t+1's loads stay IN FLIGHT
// across the barrier (the thing __syncthreads structurally forbids -- its
// implicit vmcnt(0) drain is what kept v1/v2 at 20% MfmaUtil).
// Write-after-read safety: lgkmcnt(0) drained before the barrier every wave
// crosses => tile t+2's stores (issued after it) can't race iter t-1 readers.
//
// XCD swizzle: linear wg id round-robins XCDs; map so each XCD owns 8
// contiguous m-tiles => its x-panel slice (2 MB) stays L2-resident, cutting
// A-panel load latency from L3 (~600cy) to L2 (~200cy).

template<int MODE>
__global__ __launch_bounds__(256, 2)
void gemm_bt(const unsigned short* __restrict__ A,
             const unsigned short* __restrict__ Wq,
             const unsigned short* __restrict__ Wk,
             const float* __restrict__ cosp,
             const float* __restrict__ sinp,
             unsigned short* __restrict__ outq,
             unsigned short* __restrict__ outk,
             unsigned short* __restrict__ outvt,
             float* __restrict__ outf)
{
    constexpr int K  = 1024;
    constexpr int NT = K / 32;                       // 32 K-steps
    __shared__ __align__(16) unsigned short As[3][128 * 32];
    __shared__ __align__(16) unsigned short Bs[3][128 * 32];

    const int t    = threadIdx.x;
    const int w    = t >> 6;
    const int lane = t & 63;
    const int c    = lane & 15;
    const int quad = lane >> 4;
    const int wr   = w >> 1, wc = w & 1;

    // ---- XCD-aware bijective swizzle (nwg % 8 == 0 for all modes) ----
    const int bid  = blockIdx.y * gridDim.x + blockIdx.x;  // linear dispatch id
    const int xcd  = bid & 7;
    const int slot = bid >> 3;
    const int mt   = (xcd << 3) | (slot & 7);   // 8 contiguous m-tiles per XCD
    const int rest = slot >> 3;                  // n-tile / which selector

    const int m0 = mt * 128;
    int which, n0;
    const unsigned short* W;
    if constexpr (MODE == 0) {
        which = rest >> 3;                  // 0 = Q, 1 = K
        n0    = (rest & 7) * 128;
        W     = which ? Wk : Wq;
    } else {
        which = 0;
        n0    = rest * 128;
        W     = Wq;
    }

    const int srow = t >> 2;
    const int scol = (t & 3) * 8;
    const unsigned short* ga0 = A + (size_t)(m0 + srow) * K + scol;
    const unsigned short* ga1 = A + (size_t)(m0 + srow + 64) * K + scol;
    const unsigned short* gb0 = W + (size_t)(n0 + srow) * K + scol;
    const unsigned short* gb1 = W + (size_t)(n0 + srow + 64) * K + scol;

    floatx4 acc[4][4] = {};

    const int arow = wr * 64;
    const int brow = wc * 64;

    auto stage = [&](int buf, int k0) {
        char* la = (char*)&As[buf][0] + t * 16;
        char* lb = (char*)&Bs[buf][0] + t * 16;
        gl_lds16(ga0 + k0, la);
        gl_lds16(ga1 + k0, la + 4096);
        gl_lds16(gb0 + k0, lb);
        gl_lds16(gb1 + k0, lb + 4096);
    };

    stage(0, 0);                                     // prologue: tiles 0,1 in flight
    stage(1, 32);

    for (int it = 0; it < NT; ++it) {
        const int buf = it % 3;
        // my reads of buf[it-1] are done (lgkm); my tile-it loads done (oldest 4),
        // tile-(it+1) loads REMAIN IN FLIGHT across the barrier.
        if (it + 1 < NT) asm volatile("s_waitcnt vmcnt(4) lgkmcnt(0)" ::: "memory");
        else             asm volatile("s_waitcnt vmcnt(0) lgkmcnt(0)" ::: "memory");
        __builtin_amdgcn_s_barrier();
        __builtin_amdgcn_sched_barrier(0);   // nothing floats above the barrier

        if (it + 2 < NT) stage((it + 2) % 3, (it + 2) * 32);  // into buf freed at this barrier

        bf16x8 af[4], bfr[4];
        #pragma unroll
        for (int mi = 0; mi < 4; mi++)
            af[mi] = *(const bf16x8*)&As[buf][(arow + mi * 16 + c) * 32 + quad * 8];
        #pragma unroll
        for (int ni = 0; ni < 4; ni++)
            bfr[ni] = *(const bf16x8*)&Bs[buf][(brow + ni * 16 + c) * 32 + quad * 8];
        if constexpr (MODE == 2) {
            // D[token][d]
            #pragma unroll
            for (int mi = 0; mi < 4; mi++)
                #pragma unroll
                for (int ni = 0; ni < 4; ni++)
                    acc[mi][ni] = __builtin_amdgcn_mfma_f32_16x16x32_bf16(
                        af[mi], bfr[ni], acc[mi][ni], 0, 0, 0);
        } else {
            // D[d-or-n][token]  (transposed)
            #pragma unroll
            for (int mi = 0; mi < 4; mi++)
                #pragma unroll
                for (int ni = 0; ni < 4; ni++)
                    acc[mi][ni] = __builtin_amdgcn_mfma_f32_16x16x32_bf16(
                        bfr[ni], af[mi], acc[mi][ni], 0, 0, 0);
        }
    }

    if constexpr (MODE == 1) {
        #pragma unroll
        for (int mi = 0; mi < 4; mi++) {
            int m = m0 + wr * 64 + mi * 16 + c;
            #pragma unroll
            for (int ni = 0; ni < 4; ni++) {
                int n = n0 + wc * 64 + ni * 16 + quad * 4;
                *(floatx4*)&outf[(size_t)m * 1024 + n] = acc[mi][ni];
            }
        }
    } else if constexpr (MODE == 2) {
        const int hh = (n0 + wc * 64) >> 6;
        #pragma unroll
        for (int mi = 0; mi < 4; mi++) {
            int t0 = m0 + wr * 64 + mi * 16 + quad * 4;
            int b = t0 >> 11, tt0 = t0 & 2047;
            #pragma unroll
            for (int ni = 0; ni < 4; ni++) {
                int d = ni * 16 + c;
                uint2 pk;
                pk.x = pack2bf(acc[mi][ni][0], acc[mi][ni][1]);
                pk.y = pack2bf(acc[mi][ni][2], acc[mi][ni][3]);
                *(uint2*)&outvt[((size_t)((b * 16 + hh) * 64 + d)) * 2048 + tt0] = pk;
            }
        }
    } else {
        // MODE 0: RoPE epilogue, transposed: reg r = d0+r ; col token = m
        const int hh = (n0 + wc * 64) >> 6;
        unsigned short* dst = which ? outk : outq;
        const float scale = which ? 1.0f : (0.125f * 1.44269504088896f);
        #pragma unroll
        for (int mi = 0; mi < 4; mi++) {
            int m = m0 + wr * 64 + mi * 16 + c;
            int b = m >> 11, tt = m & 2047;
            size_t obase = ((size_t)(b * 16 + hh) * 2048 + tt) * 64;
            #pragma unroll
            for (int ni = 0; ni < 4; ni++) {
                int d0 = ni * 16 + quad * 4;
                float4 cv = *(const float4*)&cosp[tt * 64 + d0];
                float4 sv = *(const float4*)&sinp[tt * 64 + d0];
                float ca[4] = {cv.x, cv.y, cv.z, cv.w};
                float sa[4] = {sv.x, sv.y, sv.z, sv.w};
                float vq[4];
                #pragma unroll
                for (int r = 0; r < 4; r++) {
                    float pr  = acc[mi][ni ^ 2][r];
                    float rot = (ni & 2) ? pr : -pr;
                    vq[r] = (acc[mi][ni][r] * ca[r] + rot * sa[r]) * scale;
                }
                uint2 pk;
                pk.x = pack2bf(vq[0], vq[1]);
                pk.y = pack2bf(vq[2], vq[3]);
                *(uint2*)&dst[obase + d0] = pk;
            }
        }
    }
}

// ---------- causal flash attention v5 (unchanged) ----------
__global__ __launch_bounds__(256)
void flash_attn(const unsigned short* __restrict__ Q,
                const unsigned short* __restrict__ Kg,
                const unsigned short* __restrict__ Vt,
                unsigned short* __restrict__ O)
{
    __shared__ __align__(16) unsigned short Ks[2][64 * 64];
    __shared__ __align__(16) unsigned short Vs[2][64 * 64];

    const int t    = threadIdx.x;
    const int w    = t >> 6;
    const int lane = t & 63;
    const int c    = lane & 15;
    const int quad = lane >> 4;

    const int bh = blockIdx.x;            // bh on x: same head's tiles share an XCD
    const int b  = bh >> 4, h = bh & 15;

    const unsigned short* qp = Q  + (size_t)bh * 2048 * 64;
    const unsigned short* kp = Kg + (size_t)bh * 2048 * 64;
    const unsigned short* vp = Vt + (size_t)bh * 64 * 2048;

    const int srow = t >> 3;
    const int sj   = (t & 7) ^ (srow & 7);

    const int qi = 31 - (int)blockIdx.y;  // LPT: largest blocks dispatched first
    const int q0 = qi * 64;
    const int qb = q0 + w * 16;

    bf16x8 qf[2];
    #pragma unroll
    for (int dc = 0; dc < 2; dc++)
        qf[dc] = *(const bf16x8*)&qp[(size_t)(qb + c) * 64 + dc * 32 + quad * 8];

    union { unsigned short us[8]; bf16x8 v; } one8;
    #pragma unroll
    for (int j = 0; j < 8; j++) one8.us[j] = 0x3F80;   // bf16(1.0)

    floatx4 o[4] = {};
    floatx4 lacc = {};

    #pragma unroll
    for (int ch = 0; ch < 2; ch++) {   // prologue stage -> buf 0
        int kr = ch * 32 + srow;
        gl_lds16(kp + (size_t)kr * 64 + sj * 8, (char*)&Ks[0][0] + ch * 4096 + t * 16);
        gl_lds16(vp + (size_t)kr * 2048 + sj * 8, (char*)&Vs[0][0] + ch * 4096 + t * 16);
    }

    const int iters = qi + 1;
    for (int it = 0; it < iters; it++) {
        const int cur = it & 1;
        const int kt0 = it * 64;
        __syncthreads();               // drains stage(cur)
        if (it + 1 < iters) {
            const int kt1 = kt0 + 64;
            #pragma unroll
            for (int ch = 0; ch < 2; ch++) {
                int kr = ch * 32 + srow;
                gl_lds16(kp + (size_t)(kt1 + kr) * 64 + sj * 8,
                         (char*)&Ks[cur ^ 1][0] + ch * 4096 + t * 16);
                gl_lds16(vp + (size_t)kr * 2048 + kt1 + sj * 8,
                         (char*)&Vs[cur ^ 1][0] + ch * 4096 + t * 16);
            }
        }
        const unsigned short* KsC = &Ks[cur][0];
        const unsigned short* VsC = &Vs[cur][0];

        // S^T = K x Q : lane holds key = mt*16+quad*4+r, qrow = qb+c
        floatx4 s[4] = {};
        #pragma unroll
        for (int dc = 0; dc < 2; dc++) {
            const int phys = (dc * 4 + quad) ^ (c & 7);
            #pragma unroll
            for (int mt = 0; mt < 4; mt++) {
                bf16x8 kb = *(const bf16x8*)&KsC[(mt * 16 + c) * 64 + phys * 8];
                s[mt] = __builtin_amdgcn_mfma_f32_16x16x32_bf16(kb, qf[dc], s[mt], 0, 0, 0);
            }
        }

        if (it == iters - 1) {         // causal mask, diagonal tile only
            #pragma unroll
            for (int mt = 0; mt < 4; mt++) {
                int keyb = kt0 + mt * 16 + quad * 4;
                #pragma unroll
                for (int r = 0; r < 4; r++)
                    if (keyb + r > qb + c) s[mt][r] = -1e30f;
            }
        }

        // static exp2 softmax numerator, packed to bf16 pairs
        uint2 pk[4];
        #pragma unroll
        for (int mt = 0; mt < 4; mt++) {
            float p0 = __builtin_amdgcn_exp2f(s[mt][0]);
            float p1 = __builtin_amdgcn_exp2f(s[mt][1]);
            float p2 = __builtin_amdgcn_exp2f(s[mt][2]);
            float p3 = __builtin_amdgcn_exp2f(s[mt][3]);
            pk[mt].x = packtrunc(p0, p1);
            pk[mt].y = packtrunc(p2, p3);
        }

        // in-register quad redistribution + PV + ones-MFMA for l
        #pragma unroll
        for (int kc = 0; kc < 2; kc++) {
            unsigned int x0 = pk[2 * kc].x;      // keys kc*32 + quad*4 + {0,1}
            unsigned int x1 = pk[2 * kc].y;      // keys kc*32 + quad*4 + {2,3}
            unsigned int x2 = pk[2 * kc + 1].x;  // keys kc*32 + 16 + quad*4 + {0,1}
            unsigned int x3 = pk[2 * kc + 1].y;  // keys kc*32 + 16 + quad*4 + {2,3}
            // swap32: x0=[A0,A1,C0,C1] x2=[A2,A3,C2,C3] (by quad, per c)
            asm("v_permlane32_swap_b32 %0, %1" : "+v"(x0), "+v"(x2));
            asm("v_permlane32_swap_b32 %0, %1" : "+v"(x1), "+v"(x3));
            // swap16: x0=[A0,A2,C0,C2]=dw0  x2=[A1,A3,C1,C3]=dw2
            asm("v_permlane16_swap_b32 %0, %1" : "+v"(x0), "+v"(x2));
            asm("v_permlane16_swap_b32 %0, %1" : "+v"(x1), "+v"(x3));
            union { unsigned int u[4]; bf16x8 v; } ap;
            ap.u[0] = x0; ap.u[1] = x1; ap.u[2] = x2; ap.u[3] = x3;

            lacc = __builtin_amdgcn_mfma_f32_16x16x32_bf16(ap.v, one8.v, lacc, 0, 0, 0);

            const int phys = (kc * 4 + quad) ^ (c & 7);
            #pragma unroll
            for (int ni = 0; ni < 4; ni++) {
                bf16x8 vb = *(const bf16x8*)&VsC[(ni * 16 + c) * 64 + phys * 8];
                o[ni] = __builtin_amdgcn_mfma_f32_16x16x32_bf16(ap.v, vb, o[ni], 0, 0, 0);
            }
        }
    }

    // epilogue: lacc[r] is l for output row quad*4+r -- no cross-lane ops
    #pragma unroll
    for (int r = 0; r < 4; r++) {
        float linv = __builtin_amdgcn_rcpf(lacc[r]);
        int qrow = qb + quad * 4 + r;
        size_t base = ((size_t)(b * 2048 + qrow)) * 1024 + h * 64;
        #pragma unroll
        for (int ni = 0; ni < 4; ni++)
            O[base + ni * 16 + c] = f2bf(o[ni][r] * linv);
    }
}

// ---------- launcher ----------

extern "C" void kernel_launch(void* const* d_in, const int* in_sizes, int n_in,
                              void* d_out, int out_size, void* d_ws, size_t ws_size,
                              hipStream_t stream) {
    const float* x    = (const float*)d_in[0];
    const float* cosp = (const float*)d_in[1];
    const float* sinp = (const float*)d_in[2];
    const float* wq   = (const float*)d_in[3];
    const float* wk   = (const float*)d_in[4];
    const float* wv   = (const float*)d_in[5];
    const float* wo   = (const float*)d_in[6];

    char* ws = (char*)d_ws;
    const size_t MB = 1024 * 1024;
    unsigned short* xb   = (unsigned short*)(ws + 0);
    unsigned short* attn = (unsigned short*)(ws + 0);       // aliases xb (stream-ordered)
    unsigned short* wqb  = (unsigned short*)(ws + 16 * MB);
    unsigned short* wkb  = (unsigned short*)(ws + 18 * MB);
    unsigned short* wvb  = (unsigned short*)(ws + 20 * MB);
    unsigned short* wob  = (unsigned short*)(ws + 22 * MB);
    unsigned short* qbuf = (unsigned short*)(ws + 24 * MB); // (B*H, T, 64)
    unsigned short* kbuf = (unsigned short*)(ws + 40 * MB); // (B*H, T, 64)
    unsigned short* vtb  = (unsigned short*)(ws + 56 * MB); // (B*H, 64, T)

    cvt_all<<<dim3(12288), 256, 0, stream>>>(x, wq, wk, wv, wo,
                                             xb, wqb, wkb, wvb, wob);

    // Q/K projection + RoPE (transposed orientation)
    gemm_bt<0><<<dim3(64, 16), 256, 0, stream>>>(xb, wqb, wkb, cosp, sinp,
                                                 qbuf, kbuf, nullptr, nullptr);
    // V projection -> V^T (orientation-1)
    gemm_bt<2><<<dim3(64, 8), 256, 0, stream>>>(xb, wvb, nullptr, nullptr, nullptr,
                                                nullptr, nullptr, vtb, nullptr);

    flash_attn<<<dim3(64, 32), 256, 0, stream>>>(qbuf, kbuf, vtb, attn);

    gemm_bt<1><<<dim3(64, 8), 256, 0, stream>>>(attn, wob, nullptr, nullptr, nullptr,
                                                nullptr, nullptr, nullptr, (float*)d_out);
}

// Round 5
// 243.794 us; speedup vs baseline: 1.0862x; 1.0862x over previous
//
#include <hip/hip_runtime.h>
#include <stdint.h>

typedef __attribute__((ext_vector_type(8))) __bf16 bf16x8;
typedef __attribute__((ext_vector_type(4))) float floatx4;

// ---------- helpers ----------

__device__ __forceinline__ unsigned short f2bf(float f) {
    unsigned int u = __float_as_uint(f);
    u += 0x7FFFu + ((u >> 16) & 1u);   // RNE
    return (unsigned short)(u >> 16);
}
__device__ __forceinline__ unsigned int pack2bf(float lo, float hi) {
    return (unsigned int)f2bf(lo) | ((unsigned int)f2bf(hi) << 16);
}
// truncating f32->bf16 pack of two values in ONE v_perm_b32
__device__ __forceinline__ unsigned int packtrunc(float lo, float hi) {
    return __builtin_amdgcn_perm(__float_as_uint(hi), __float_as_uint(lo), 0x07060302u);
}

__device__ __forceinline__ void gl_lds16(const void* g, void* l) {
    __builtin_amdgcn_global_load_lds(
        (const __attribute__((address_space(1))) void*)g,
        (__attribute__((address_space(3))) void*)l, 16, 0, 0);
}

// ---------- fp32 -> bf16 convert (x + all 4 weights in one launch) ----------

__global__ void cvt_all(const float* __restrict__ x,  const float* __restrict__ wq,
                        const float* __restrict__ wk, const float* __restrict__ wv,
                        const float* __restrict__ wo,
                        unsigned short* __restrict__ xb,  unsigned short* __restrict__ wqb,
                        unsigned short* __restrict__ wkb, unsigned short* __restrict__ wvb,
                        unsigned short* __restrict__ wob) {
    int i = blockIdx.x * blockDim.x + threadIdx.x;   // float4 index, 3145728 total
    const float* in; unsigned short* out; int idx;
    if (i < 2097152) { in = x; out = xb; idx = i; }
    else {
        int j = i - 2097152; int wsel = j >> 18; idx = j & 262143;
        in  = (wsel == 0) ? wq  : (wsel == 1) ? wk  : (wsel == 2) ? wv  : wo;
        out = (wsel == 0) ? wqb : (wsel == 1) ? wkb : (wsel == 2) ? wvb : wob;
    }
    float4 v = ((const float4*)in)[idx];
    ushort4 o;
    o.x = f2bf(v.x); o.y = f2bf(v.y); o.z = f2bf(v.z); o.w = f2bf(v.w);
    ((ushort4*)out)[idx] = o;
}

// ---------- GEMM: C = A @ W^T  (A: (M,1024) bf16 rm, W: (N,1024) bf16 rm)
// v4: round-1 serial 2-phase structure (proven fastest), but:
//  * BK=64: halves the number of barrier-drain stalls per block (32 -> 16),
//    doubling MFMA work amortized per stall. LDS 32 KB.
//  * XOR-swizzled staging (pre-swizzled global source col-chunk, linear LDS
//    dest -- rule 21 -- and matching XOR on the ds_read side). Conflict-free
//    ds_read_b128 (2 lanes/bank = free). Same pattern as flash_attn's K/V.
//  * MODE 0 = MERGED QKV projection: blockIdx.y 0-7 = Q (+RoPE), 8-15 = K
//    (+RoPE), 16-23 = V (V^T packed stores). 1536 blocks = 6/CU: V-blocks'
//    MFMA phases fill Q/K-blocks' drain stalls, one launch tail not two.
//  * No XCD swizzle (round-3 evidence: it RAISED FETCH_SIZE 25.5->36.4 MB).
// MODE 1: out-proj, transposed orientation, float4 fp32 stores.

template<int MODE>
__global__ __launch_bounds__(256, 2)
void gemm_bt(const unsigned short* __restrict__ A,
             const unsigned short* __restrict__ Wq,
             const unsigned short* __restrict__ Wk,
             const unsigned short* __restrict__ Wv,
             const float* __restrict__ cosp,
             const float* __restrict__ sinp,
             unsigned short* __restrict__ outq,
             unsigned short* __restrict__ outk,
             unsigned short* __restrict__ outvt,
             float* __restrict__ outf)
{
    constexpr int K = 1024;
    __shared__ __align__(16) unsigned short As[128 * 64];
    __shared__ __align__(16) unsigned short Bs[128 * 64];

    const int t    = threadIdx.x;
    const int w    = t >> 6;
    const int lane = t & 63;
    const int c    = lane & 15;
    const int quad = lane >> 4;
    const int wr   = w >> 1, wc = w & 1;

    const int m0 = blockIdx.x * 128;
    int which3, n0;
    const unsigned short* W;
    if constexpr (MODE == 0) {
        which3 = blockIdx.y >> 3;           // 0 = Q, 1 = K, 2 = V
        n0     = (blockIdx.y & 7) * 128;
        W      = (which3 == 0) ? Wq : (which3 == 1) ? Wk : Wv;
    } else {
        which3 = 0;
        n0     = blockIdx.y * 128;
        W      = Wq;
    }
    const bool vmode = (MODE == 0) && (which3 == 2);

    // staging: 128 rows x 64 cols per operand; thread t loads 4 chunks of 16B
    // per operand. row = 32*j + (t>>3), physical col-chunk = t&7, global
    // col-chunk = (t&7) ^ (row&7)  (involution; LDS dest stays linear).
    const int srow = t >> 3;                       // 0..31
    const int sj   = ((t & 7) ^ (srow & 7)) * 8;   // swizzled source elem offset
    const unsigned short* ga[4];
    const unsigned short* gb[4];
    #pragma unroll
    for (int j = 0; j < 4; j++) {
        ga[j] = A + (size_t)(m0 + srow + 32 * j) * K + sj;
        gb[j] = W + (size_t)(n0 + srow + 32 * j) * K + sj;
    }

    floatx4 acc[4][4] = {};

    const int arow = wr * 64;
    const int brow = wc * 64;

    for (int k0 = 0; k0 < K; k0 += 64) {
        __syncthreads();                 // WAR: all waves done reading prev tile
        #pragma unroll
        for (int j = 0; j < 4; j++) {
            gl_lds16(ga[j] + k0, (char*)As + j * 4096 + t * 16);
            gl_lds16(gb[j] + k0, (char*)Bs + j * 4096 + t * 16);
        }
        __syncthreads();                 // drain: tile visible to all waves
        #pragma unroll
        for (int kk = 0; kk < 2; kk++) {
            // global col-chunk kk*4+quad, de-swizzle with row&7 (= c&7 here)
            const int phys = (((kk << 2) | quad) ^ (c & 7)) * 8;
            bf16x8 af[4], bfr[4];
            #pragma unroll
            for (int mi = 0; mi < 4; mi++)
                af[mi] = *(const bf16x8*)&As[(arow + mi * 16 + c) * 64 + phys];
            #pragma unroll
            for (int ni = 0; ni < 4; ni++)
                bfr[ni] = *(const bf16x8*)&Bs[(brow + ni * 16 + c) * 64 + phys];
            if (vmode) {
                // D[token][d]
                #pragma unroll
                for (int mi = 0; mi < 4; mi++)
                    #pragma unroll
                    for (int ni = 0; ni < 4; ni++)
                        acc[mi][ni] = __builtin_amdgcn_mfma_f32_16x16x32_bf16(
                            af[mi], bfr[ni], acc[mi][ni], 0, 0, 0);
            } else {
                // D[d-or-n][token]  (transposed)
                #pragma unroll
                for (int mi = 0; mi < 4; mi++)
                    #pragma unroll
                    for (int ni = 0; ni < 4; ni++)
                        acc[mi][ni] = __builtin_amdgcn_mfma_f32_16x16x32_bf16(
                            bfr[ni], af[mi], acc[mi][ni], 0, 0, 0);
            }
        }
    }

    if constexpr (MODE == 1) {
        #pragma unroll
        for (int mi = 0; mi < 4; mi++) {
            int m = m0 + wr * 64 + mi * 16 + c;
            #pragma unroll
            for (int ni = 0; ni < 4; ni++) {
                int n = n0 + wc * 64 + ni * 16 + quad * 4;
                *(floatx4*)&outf[(size_t)m * 1024 + n] = acc[mi][ni];
            }
        }
    } else if (vmode) {
        // V: packed V^T stores
        const int hh = (n0 + wc * 64) >> 6;
        #pragma unroll
        for (int mi = 0; mi < 4; mi++) {
            int t0 = m0 + wr * 64 + mi * 16 + quad * 4;
            int b = t0 >> 11, tt0 = t0 & 2047;
            #pragma unroll
            for (int ni = 0; ni < 4; ni++) {
                int d = ni * 16 + c;
                uint2 pk;
                pk.x = pack2bf(acc[mi][ni][0], acc[mi][ni][1]);
                pk.y = pack2bf(acc[mi][ni][2], acc[mi][ni][3]);
                *(uint2*)&outvt[((size_t)((b * 16 + hh) * 64 + d)) * 2048 + tt0] = pk;
            }
        }
    } else {
        // Q/K: RoPE epilogue, transposed: reg r = d0+r ; col token = m
        const int hh = (n0 + wc * 64) >> 6;
        unsigned short* dst = which3 ? outk : outq;
        const float scale = which3 ? 1.0f : (0.125f * 1.44269504088896f);
        #pragma unroll
        for (int mi = 0; mi < 4; mi++) {
            int m = m0 + wr * 64 + mi * 16 + c;
            int b = m >> 11, tt = m & 2047;
            size_t obase = ((size_t)(b * 16 + hh) * 2048 + tt) * 64;
            #pragma unroll
            for (int ni = 0; ni < 4; ni++) {
                int d0 = ni * 16 + quad * 4;
                float4 cv = *(const float4*)&cosp[tt * 64 + d0];
                float4 sv = *(const float4*)&sinp[tt * 64 + d0];
                float ca[4] = {cv.x, cv.y, cv.z, cv.w};
                float sa[4] = {sv.x, sv.y, sv.z, sv.w};
                float vq[4];
                #pragma unroll
                for (int r = 0; r < 4; r++) {
                    float pr  = acc[mi][ni ^ 2][r];
                    float rot = (ni & 2) ? pr : -pr;
                    vq[r] = (acc[mi][ni][r] * ca[r] + rot * sa[r]) * scale;
                }
                uint2 pk;
                pk.x = pack2bf(vq[0], vq[1]);
                pk.y = pack2bf(vq[2], vq[3]);
                *(uint2*)&dst[obase + d0] = pk;
            }
        }
    }
}

// ---------- causal flash attention v5 (unchanged) ----------
__global__ __launch_bounds__(256)
void flash_attn(const unsigned short* __restrict__ Q,
                const unsigned short* __restrict__ Kg,
                const unsigned short* __restrict__ Vt,
                unsigned short* __restrict__ O)
{
    __shared__ __align__(16) unsigned short Ks[2][64 * 64];
    __shared__ __align__(16) unsigned short Vs[2][64 * 64];

    const int t    = threadIdx.x;
    const int w    = t >> 6;
    const int lane = t & 63;
    const int c    = lane & 15;
    const int quad = lane >> 4;

    const int bh = blockIdx.x;            // bh on x: same head's tiles share an XCD
    const int b  = bh >> 4, h = bh & 15;

    const unsigned short* qp = Q  + (size_t)bh * 2048 * 64;
    const unsigned short* kp = Kg + (size_t)bh * 2048 * 64;
    const unsigned short* vp = Vt + (size_t)bh * 64 * 2048;

    const int srow = t >> 3;
    const int sj   = (t & 7) ^ (srow & 7);

    const int qi = 31 - (int)blockIdx.y;  // LPT: largest blocks dispatched first
    const int q0 = qi * 64;
    const int qb = q0 + w * 16;

    bf16x8 qf[2];
    #pragma unroll
    for (int dc = 0; dc < 2; dc++)
        qf[dc] = *(const bf16x8*)&qp[(size_t)(qb + c) * 64 + dc * 32 + quad * 8];

    union { unsigned short us[8]; bf16x8 v; } one8;
    #pragma unroll
    for (int j = 0; j < 8; j++) one8.us[j] = 0x3F80;   // bf16(1.0)

    floatx4 o[4] = {};
    floatx4 lacc = {};

    #pragma unroll
    for (int ch = 0; ch < 2; ch++) {   // prologue stage -> buf 0
        int kr = ch * 32 + srow;
        gl_lds16(kp + (size_t)kr * 64 + sj * 8, (char*)&Ks[0][0] + ch * 4096 + t * 16);
        gl_lds16(vp + (size_t)kr * 2048 + sj * 8, (char*)&Vs[0][0] + ch * 4096 + t * 16);
    }

    const int iters = qi + 1;
    for (int it = 0; it < iters; it++) {
        const int cur = it & 1;
        const int kt0 = it * 64;
        __syncthreads();               // drains stage(cur)
        if (it + 1 < iters) {
            const int kt1 = kt0 + 64;
            #pragma unroll
            for (int ch = 0; ch < 2; ch++) {
                int kr = ch * 32 + srow;
                gl_lds16(kp + (size_t)(kt1 + kr) * 64 + sj * 8,
                         (char*)&Ks[cur ^ 1][0] + ch * 4096 + t * 16);
                gl_lds16(vp + (size_t)kr * 2048 + kt1 + sj * 8,
                         (char*)&Vs[cur ^ 1][0] + ch * 4096 + t * 16);
            }
        }
        const unsigned short* KsC = &Ks[cur][0];
        const unsigned short* VsC = &Vs[cur][0];

        // S^T = K x Q : lane holds key = mt*16+quad*4+r, qrow = qb+c
        floatx4 s[4] = {};
        #pragma unroll
        for (int dc = 0; dc < 2; dc++) {
            const int phys = (dc * 4 + quad) ^ (c & 7);
            #pragma unroll
            for (int mt = 0; mt < 4; mt++) {
                bf16x8 kb = *(const bf16x8*)&KsC[(mt * 16 + c) * 64 + phys * 8];
                s[mt] = __builtin_amdgcn_mfma_f32_16x16x32_bf16(kb, qf[dc], s[mt], 0, 0, 0);
            }
        }

        if (it == iters - 1) {         // causal mask, diagonal tile only
            #pragma unroll
            for (int mt = 0; mt < 4; mt++) {
                int keyb = kt0 + mt * 16 + quad * 4;
                #pragma unroll
                for (int r = 0; r < 4; r++)
                    if (keyb + r > qb + c) s[mt][r] = -1e30f;
            }
        }

        // static exp2 softmax numerator, packed to bf16 pairs
        uint2 pk[4];
        #pragma unroll
        for (int mt = 0; mt < 4; mt++) {
            float p0 = __builtin_amdgcn_exp2f(s[mt][0]);
            float p1 = __builtin_amdgcn_exp2f(s[mt][1]);
            float p2 = __builtin_amdgcn_exp2f(s[mt][2]);
            float p3 = __builtin_amdgcn_exp2f(s[mt][3]);
            pk[mt].x = packtrunc(p0, p1);
            pk[mt].y = packtrunc(p2, p3);
        }

        // in-register quad redistribution + PV + ones-MFMA for l
        #pragma unroll
        for (int kc = 0; kc < 2; kc++) {
            unsigned int x0 = pk[2 * kc].x;      // keys kc*32 + quad*4 + {0,1}
            unsigned int x1 = pk[2 * kc].y;      // keys kc*32 + quad*4 + {2,3}
            unsigned int x2 = pk[2 * kc + 1].x;  // keys kc*32 + 16 + quad*4 + {0,1}
            unsigned int x3 = pk[2 * kc + 1].y;  // keys kc*32 + 16 + quad*4 + {2,3}
            // swap32: x0=[A0,A1,C0,C1] x2=[A2,A3,C2,C3] (by quad, per c)
            asm("v_permlane32_swap_b32 %0, %1" : "+v"(x0), "+v"(x2));
            asm("v_permlane32_swap_b32 %0, %1" : "+v"(x1), "+v"(x3));
            // swap16: x0=[A0,A2,C0,C2]=dw0  x2=[A1,A3,C1,C3]=dw2
            asm("v_permlane16_swap_b32 %0, %1" : "+v"(x0), "+v"(x2));
            asm("v_permlane16_swap_b32 %0, %1" : "+v"(x1), "+v"(x3));
            union { unsigned int u[4]; bf16x8 v; } ap;
            ap.u[0] = x0; ap.u[1] = x1; ap.u[2] = x2; ap.u[3] = x3;

            lacc = __builtin_amdgcn_mfma_f32_16x16x32_bf16(ap.v, one8.v, lacc, 0, 0, 0);

            const int phys = (kc * 4 + quad) ^ (c & 7);
            #pragma unroll
            for (int ni = 0; ni < 4; ni++) {
                bf16x8 vb = *(const bf16x8*)&VsC[(ni * 16 + c) * 64 + phys * 8];
                o[ni] = __builtin_amdgcn_mfma_f32_16x16x32_bf16(ap.v, vb, o[ni], 0, 0, 0);
            }
        }
    }

    // epilogue: lacc[r] is l for output row quad*4+r -- no cross-lane ops
    #pragma unroll
    for (int r = 0; r < 4; r++) {
        float linv = __builtin_amdgcn_rcpf(lacc[r]);
        int qrow = qb + quad * 4 + r;
        size_t base = ((size_t)(b * 2048 + qrow)) * 1024 + h * 64;
        #pragma unroll
        for (int ni = 0; ni < 4; ni++)
            O[base + ni * 16 + c] = f2bf(o[ni][r] * linv);
    }
}

// ---------- launcher ----------

extern "C" void kernel_launch(void* const* d_in, const int* in_sizes, int n_in,
                              void* d_out, int out_size, void* d_ws, size_t ws_size,
                              hipStream_t stream) {
    const float* x    = (const float*)d_in[0];
    const float* cosp = (const float*)d_in[1];
    const float* sinp = (const float*)d_in[2];
    const float* wq   = (const float*)d_in[3];
    const float* wk   = (const float*)d_in[4];
    const float* wv   = (const float*)d_in[5];
    const float* wo   = (const float*)d_in[6];

    char* ws = (char*)d_ws;
    const size_t MB = 1024 * 1024;
    unsigned short* xb   = (unsigned short*)(ws + 0);
    unsigned short* attn = (unsigned short*)(ws + 0);       // aliases xb (stream-ordered)
    unsigned short* wqb  = (unsigned short*)(ws + 16 * MB);
    unsigned short* wkb  = (unsigned short*)(ws + 18 * MB);
    unsigned short* wvb  = (unsigned short*)(ws + 20 * MB);
    unsigned short* wob  = (unsigned short*)(ws + 22 * MB);
    unsigned short* qbuf = (unsigned short*)(ws + 24 * MB); // (B*H, T, 64)
    unsigned short* kbuf = (unsigned short*)(ws + 40 * MB); // (B*H, T, 64)
    unsigned short* vtb  = (unsigned short*)(ws + 56 * MB); // (B*H, 64, T)

    cvt_all<<<dim3(12288), 256, 0, stream>>>(x, wq, wk, wv, wo,
                                             xb, wqb, wkb, wvb, wob);

    // merged QKV projection (+RoPE for Q/K, V^T packing for V)
    gemm_bt<0><<<dim3(64, 24), 256, 0, stream>>>(xb, wqb, wkb, wvb, cosp, sinp,
                                                 qbuf, kbuf, vtb, nullptr);

    flash_attn<<<dim3(64, 32), 256, 0, stream>>>(qbuf, kbuf, vtb, attn);

    gemm_bt<1><<<dim3(64, 8), 256, 0, stream>>>(attn, wob, nullptr, nullptr, nullptr, nullptr,
                                                nullptr, nullptr, nullptr, (float*)d_out);
}